// Round 6
// baseline (4470.226 us; speedup 1.0000x reference)
//
#include <hip/hip_runtime.h>

// ContinuousLSTMLayer B=256,S=512,F=64,H=128; 8192 sequential RK4 stages.
// MFMA broadcast-A persistent kernel, v3:
//   256 blocks x 256 threads = exactly 1 block/CU, 1 wave/SIMD.
//   Wave wv owns n in {16wv..16wv+15} u {64+16wv..}: 2 ntiles x 4 gates.
//   Per stage: 4 ds_read_b128 (h A-frags, shared by all 8 (g,nt) combos),
//   32 MFMAs (two depth-2 chains per combo), ~95 VALU tail, 1 barrier.
//   Rationale (R2-R5 post-mortems): per-CU LDS read-issue (4 reads x waves/CU)
//   and VALU issue contention (waves/SIMD) were the binding terms at 512thr;
//   this layout cuts LDS reads/CU 64->16 and waves/SIMD 4->1.
//   All weight B-frags resident (AGPR-resident is fine: R5 showed MFMA reads
//   B directly from AGPR, no copies). 16 stages fully unrolled.

#define B_N 256
#define S_N 512
#define F_N 64
#define H_N 128

typedef _Float16 v8h __attribute__((ext_vector_type(8)));
typedef float v4f __attribute__((ext_vector_type(4)));

// sigmoid via exp2 + rcp (overflow-safe: rcp(inf)=0)
static __device__ __forceinline__ float sigm(float x) {
  float e = __builtin_amdgcn_exp2f(-1.442695040888963f * x);
  return __builtin_amdgcn_rcpf(1.0f + e);
}

__global__ void __launch_bounds__(256, 1) clstm_mfma3(
    const float* __restrict__ x,    // [B,S,F] f32
    const float* __restrict__ td,   // [B,S]   f32
    const float* __restrict__ Wi, const float* __restrict__ bi,
    const float* __restrict__ Wf, const float* __restrict__ bff,
    const float* __restrict__ Wo, const float* __restrict__ bo,
    const float* __restrict__ Wg, const float* __restrict__ bg,
    float* __restrict__ out)        // [B,S,H] f32
{
  const int b    = blockIdx.x;
  const int t    = threadIdx.x;
  const int wv   = t >> 6;     // wave 0..3
  const int l    = t & 63;
  const int col  = l & 15;
  const int quad = l >> 4;
  const int nn[2] = { wv * 16 + col, 64 + wv * 16 + col };

  const float* Wptr[4] = {Wi, Wf, Wo, Wg};

  // Resident B-frags. Bh: h-part rows 64..191 (4 kt), Bx: x-part rows 0..63.
  // Lane holds B[k = kt*32 + quad*8 + j][n] as 8 f16.
  v8h Bh[4][2][4];
  v8h Bx[4][2][2];
  float bias[4][2];
#pragma unroll
  for (int g = 0; g < 4; ++g) {
    const float* W = Wptr[g];
#pragma unroll
    for (int nt = 0; nt < 2; ++nt) {
      const int n = nn[nt];
#pragma unroll
      for (int kt = 0; kt < 4; ++kt) {
        v8h f;
#pragma unroll
        for (int j = 0; j < 8; ++j)
          f[j] = (_Float16)W[(64 + kt * 32 + quad * 8 + j) * H_N + n];
        Bh[g][nt][kt] = f;
      }
#pragma unroll
      for (int kt = 0; kt < 2; ++kt) {
        v8h f;
#pragma unroll
        for (int j = 0; j < 8; ++j)
          f[j] = (_Float16)W[(kt * 32 + quad * 8 + j) * H_N + n];
        Bx[g][nt][kt] = f;
      }
      bias[g][nt] = (g == 0 ? bi : g == 1 ? bff : g == 2 ? bo : bg)[n];
    }
  }

  __shared__ alignas(16) _Float16 lds_h[2][H_N];  // double-buffered h (f16)
  __shared__ alignas(16) _Float16 lds_x[F_N];     // current x_t (f16)
  __shared__ float lds_td[S_N];

  lds_td[t]       = td[b * S_N + t];
  lds_td[t + 256] = td[b * S_N + t + 256];
  if (t < 32) {
    const float* xr = x + (size_t)b * S_N * F_N;
    lds_x[2 * t]     = (_Float16)xr[2 * t];
    lds_x[2 * t + 1] = (_Float16)xr[2 * t + 1];
  }
  if (t < H_N) lds_h[0][t] = (_Float16)0.0f;
  __syncthreads();

  float h0v[2] = {0.f, 0.f}, c0v[2] = {0.f, 0.f};
  float h_ev[2] = {0.f, 0.f}, c_ev[2] = {0.f, 0.f};
  float sum_h[2] = {0.f, 0.f}, sum_c[2] = {0.f, 0.f};
  const v4f zf = {0.f, 0.f, 0.f, 0.f};

  for (int s = 0; s < S_N; ++s) {
    float dt  = fminf(lds_td[s], 1.0f) * 0.25f;  // MAX_DT / ODE_STEPS
    float hdt = 0.5f * dt;
    float d6  = dt * (1.0f / 6.0f);

    // x-projection + bias once per time step (16 MFMAs, amortized /16 stages)
    v8h ax0 = *(const v8h*)(lds_x + quad * 8);
    v8h ax1 = *(const v8h*)(lds_x + 32 + quad * 8);
    v4f xpD[4][2];
#pragma unroll
    for (int g = 0; g < 4; ++g)
#pragma unroll
      for (int nt = 0; nt < 2; ++nt) {
        float bv = bias[g][nt];
        v4f cbv = {bv, bv, bv, bv};
        v4f a = __builtin_amdgcn_mfma_f32_16x16x32_f16(ax0, Bx[g][nt][0], cbv, 0, 0, 0);
        xpD[g][nt] = __builtin_amdgcn_mfma_f32_16x16x32_f16(ax1, Bx[g][nt][1], a, 0, 0, 0);
      }

    // prefetch next x row into regs (consumed at last stage of this step)
    float xn0 = 0.f, xn1 = 0.f;
    if (t < 32 && s + 1 < S_N) {
      const float* xr = x + (size_t)(b * S_N + s + 1) * F_N;
      xn0 = xr[2 * t]; xn1 = xr[2 * t + 1];
    }

#pragma unroll
    for (int ode = 0; ode < 4; ++ode) {
#pragma unroll
      for (int st = 0; st < 4; ++st) {
        const _Float16* hb = lds_h[st & 1];
        v8h ah0 = *(const v8h*)(hb + quad * 8);
        v8h ah1 = *(const v8h*)(hb + 32 + quad * 8);
        v8h ah2 = *(const v8h*)(hb + 64 + quad * 8);
        v8h ah3 = *(const v8h*)(hb + 96 + quad * 8);

        float pre[4][2];
#pragma unroll
        for (int g = 0; g < 4; ++g)
#pragma unroll
          for (int nt = 0; nt < 2; ++nt) {
            v4f c02 = __builtin_amdgcn_mfma_f32_16x16x32_f16(ah0, Bh[g][nt][0], xpD[g][nt], 0, 0, 0);
            c02 = __builtin_amdgcn_mfma_f32_16x16x32_f16(ah1, Bh[g][nt][1], c02, 0, 0, 0);
            v4f c13 = __builtin_amdgcn_mfma_f32_16x16x32_f16(ah2, Bh[g][nt][2], zf, 0, 0, 0);
            c13 = __builtin_amdgcn_mfma_f32_16x16x32_f16(ah3, Bh[g][nt][3], c13, 0, 0, 0);
            pre[g][nt] = c02[0] + c13[0];
          }

        float hnx[2], cnx[2];
#pragma unroll
        for (int nt = 0; nt < 2; ++nt) {
          float ai = sigm(pre[0][nt]);
          float af = sigm(pre[1][nt]);
          float ao = sigm(pre[2][nt]);
          float ag = fmaf(2.0f, sigm(2.0f * pre[3][nt]), -1.0f);   // tanh
          float tc = fmaf(2.0f, sigm(2.0f * c_ev[nt]), -1.0f);     // tanh(c)
          float kc = fmaf(ai, ag, (af - 1.0f) * c_ev[nt]);         // i*g+f*c-c
          float kh = fmaf(ao, tc, -h_ev[nt]);                      // o*tanh(c)-h

          if (st == 0) {
            sum_h[nt] = kh; sum_c[nt] = kc;
            hnx[nt] = fmaf(hdt, kh, h0v[nt]); cnx[nt] = fmaf(hdt, kc, c0v[nt]);
          } else if (st == 1) {
            sum_h[nt] = fmaf(2.f, kh, sum_h[nt]); sum_c[nt] = fmaf(2.f, kc, sum_c[nt]);
            hnx[nt] = fmaf(hdt, kh, h0v[nt]); cnx[nt] = fmaf(hdt, kc, c0v[nt]);
          } else if (st == 2) {
            sum_h[nt] = fmaf(2.f, kh, sum_h[nt]); sum_c[nt] = fmaf(2.f, kc, sum_c[nt]);
            hnx[nt] = fmaf(dt, kh, h0v[nt]); cnx[nt] = fmaf(dt, kc, c0v[nt]);
          } else {
            sum_h[nt] += kh; sum_c[nt] += kc;
            h0v[nt] = fmaf(d6, sum_h[nt], h0v[nt]);
            c0v[nt] = fmaf(d6, sum_c[nt], c0v[nt]);
            hnx[nt] = h0v[nt]; cnx[nt] = c0v[nt];
          }
        }

        if (quad == 0) {
          lds_h[(st & 1) ^ 1][nn[0]] = (_Float16)hnx[0];
          lds_h[(st & 1) ^ 1][nn[1]] = (_Float16)hnx[1];
        }
        if (st == 3 && ode == 3 && t < 32 && s + 1 < S_N) {
          lds_x[2 * t]     = (_Float16)xn0;
          lds_x[2 * t + 1] = (_Float16)xn1;
        }
        __syncthreads();
        h_ev[0] = hnx[0]; c_ev[0] = cnx[0];
        h_ev[1] = hnx[1]; c_ev[1] = cnx[1];
      }
    }

    if (quad == 0) {
      out[(size_t)(b * S_N + s) * H_N + nn[0]] = h0v[0];
      out[(size_t)(b * S_N + s) * H_N + nn[1]] = h0v[1];
    }
  }
}

extern "C" void kernel_launch(void* const* d_in, const int* in_sizes, int n_in,
                              void* d_out, int out_size, void* d_ws, size_t ws_size,
                              hipStream_t stream) {
  (void)in_sizes; (void)n_in; (void)d_ws; (void)ws_size; (void)out_size;
  clstm_mfma3<<<B_N, 256, 0, stream>>>(
      (const float*)d_in[0],  // x
      (const float*)d_in[1],  // time_diffs
      (const float*)d_in[2], (const float*)d_in[3],   // W_i, b_i
      (const float*)d_in[4], (const float*)d_in[5],   // W_f, b_f
      (const float*)d_in[6], (const float*)d_in[7],   // W_o, b_o
      (const float*)d_in[8], (const float*)d_in[9],   // W_g, b_g
      (float*)d_out);
}

// Round 7
// 3695.524 us; speedup vs baseline: 1.2096x; 1.2096x over previous
//
#include <hip/hip_runtime.h>

// ContinuousLSTMLayer B=256,S=512,F=64,H=128; 8192 sequential RK4 stages.
// v4 = R4 structure (best: 3790us) + three deltas:
//  1. Fragment regs pinned to arch VGPRs via asm("":"+v") — R4's VGPR_Count=104
//     proves frags sat in AGPRs; if MFMA B-operands were materialized with
//     per-use v_accvgpr_read (~64 inst/stage), this removes them.
//  2. Full 16-stage unroll (no ode-loop overhead, immediate LDS offsets).
//  3. RK bookkeeping (sum updates, h_ev/c_ev) moved AFTER __syncthreads —
//     shortens the pre-barrier serial chain that gates wave convergence.
// Layout: 512 thr / 8 waves; wave wv owns n in [16wv,16wv+16) for all 4
// gates (broadcast-A MFMA -> D replicated, i/f/o/g land on the same lane;
// no cross-lane ops, 1 barrier per stage).

#define B_N 256
#define S_N 512
#define F_N 64
#define H_N 128

typedef _Float16 v8h __attribute__((ext_vector_type(8)));
typedef float v4f __attribute__((ext_vector_type(4)));

#define PIN_V(x) asm("" : "+v"(x))

// sigmoid via exp2 + rcp (overflow-safe: rcp(inf)=0)
static __device__ __forceinline__ float sigm(float x) {
  float e = __builtin_amdgcn_exp2f(-1.442695040888963f * x);
  return __builtin_amdgcn_rcpf(1.0f + e);
}

__global__ void __launch_bounds__(512, 2) clstm_mfma4(
    const float* __restrict__ x,    // [B,S,F] f32
    const float* __restrict__ td,   // [B,S]   f32
    const float* __restrict__ Wi, const float* __restrict__ bi,
    const float* __restrict__ Wf, const float* __restrict__ bff,
    const float* __restrict__ Wo, const float* __restrict__ bo,
    const float* __restrict__ Wg, const float* __restrict__ bg,
    float* __restrict__ out)        // [B,S,H] f32
{
  const int b    = blockIdx.x;
  const int t    = threadIdx.x;
  const int wv   = t >> 6;     // wave 0..7 -> n-tile
  const int l    = t & 63;
  const int col  = l & 15;
  const int quad = l >> 4;
  const int n    = wv * 16 + col;

  const float* Wptr[4] = {Wi, Wf, Wo, Wg};

  // Resident B-frags, pinned to arch VGPRs.
  // Bh: h-part rows 64..191 (kt 0..3); Bx: x-part rows 0..63 (kt 0..1).
  // Lane holds B[k = kt*32 + quad*8 + j][n] as 8 f16 (4 VGPRs each).
  v8h Bh[4][4];
  v8h Bx[4][2];
#pragma unroll
  for (int g = 0; g < 4; ++g) {
    const float* W = Wptr[g];
#pragma unroll
    for (int kt = 0; kt < 4; ++kt) {
      v8h f;
#pragma unroll
      for (int j = 0; j < 8; ++j)
        f[j] = (_Float16)W[(64 + kt * 32 + quad * 8 + j) * H_N + n];
      Bh[g][kt] = f;
      PIN_V(Bh[g][kt]);
    }
#pragma unroll
    for (int kt = 0; kt < 2; ++kt) {
      v8h f;
#pragma unroll
      for (int j = 0; j < 8; ++j)
        f[j] = (_Float16)W[(kt * 32 + quad * 8 + j) * H_N + n];
      Bx[g][kt] = f;
      PIN_V(Bx[g][kt]);
    }
  }
  float bias[4];
#pragma unroll
  for (int g = 0; g < 4; ++g)
    bias[g] = (g == 0 ? bi : g == 1 ? bff : g == 2 ? bo : bg)[n];

  __shared__ alignas(16) _Float16 lds_h[2][H_N];  // double-buffered h (f16)
  __shared__ alignas(16) _Float16 lds_x[F_N];     // current x_t (f16)
  __shared__ float lds_td[S_N];

  lds_td[t] = td[b * S_N + t];
  if (t < 32) {
    const float* xr = x + (size_t)b * S_N * F_N;
    lds_x[2 * t]     = (_Float16)xr[2 * t];
    lds_x[2 * t + 1] = (_Float16)xr[2 * t + 1];
  }
  if (t < H_N) lds_h[0][t] = (_Float16)0.0f;
  __syncthreads();

  float h0v = 0.f, c0v = 0.f;
  float h_ev = 0.f, c_ev = 0.f;
  float sum_h = 0.f, sum_c = 0.f;
  const v4f zf = {0.f, 0.f, 0.f, 0.f};

  for (int s = 0; s < S_N; ++s) {
    float dt  = fminf(lds_td[s], 1.0f) * 0.25f;  // MAX_DT / ODE_STEPS
    float hdt = 0.5f * dt;
    float d6  = dt * (1.0f / 6.0f);

    // x-projection + bias once per time step (8 MFMAs, amortized /16 stages)
    v8h ax0 = *(const v8h*)(lds_x + quad * 8);
    v8h ax1 = *(const v8h*)(lds_x + 32 + quad * 8);
    v4f xpD[4];
#pragma unroll
    for (int g = 0; g < 4; ++g) {
      float bv = bias[g];
      v4f cbv = {bv, bv, bv, bv};
      v4f a = __builtin_amdgcn_mfma_f32_16x16x32_f16(ax0, Bx[g][0], cbv, 0, 0, 0);
      xpD[g] = __builtin_amdgcn_mfma_f32_16x16x32_f16(ax1, Bx[g][1], a, 0, 0, 0);
    }

    // prefetch next x row into regs (consumed at last stage of this step)
    float xn0 = 0.f, xn1 = 0.f;
    if (t < 32 && s + 1 < S_N) {
      const float* xr = x + (size_t)(b * S_N + s + 1) * F_N;
      xn0 = xr[2 * t]; xn1 = xr[2 * t + 1];
    }

#pragma unroll
    for (int ode = 0; ode < 4; ++ode) {
#pragma unroll
      for (int st = 0; st < 4; ++st) {
        const _Float16* hb = lds_h[st & 1];
        v8h ah0 = *(const v8h*)(hb + quad * 8);
        v8h ah1 = *(const v8h*)(hb + 32 + quad * 8);
        v8h ah2 = *(const v8h*)(hb + 64 + quad * 8);
        v8h ah3 = *(const v8h*)(hb + 96 + quad * 8);

        // per gate: two depth-2 MFMA chains + add (R4-proven)
        float pre[4];
#pragma unroll
        for (int g = 0; g < 4; ++g) {
          v4f c02 = __builtin_amdgcn_mfma_f32_16x16x32_f16(ah0, Bh[g][0], xpD[g], 0, 0, 0);
          c02 = __builtin_amdgcn_mfma_f32_16x16x32_f16(ah1, Bh[g][1], c02, 0, 0, 0);
          v4f c13 = __builtin_amdgcn_mfma_f32_16x16x32_f16(ah2, Bh[g][2], zf, 0, 0, 0);
          c13 = __builtin_amdgcn_mfma_f32_16x16x32_f16(ah3, Bh[g][3], c13, 0, 0, 0);
          pre[g] = c02[0] + c13[0];
        }

        float ai = sigm(pre[0]);
        float af = sigm(pre[1]);
        float ao = sigm(pre[2]);
        float ag = fmaf(2.0f, sigm(2.0f * pre[3]), -1.0f);   // tanh
        float tc = fmaf(2.0f, sigm(2.0f * c_ev), -1.0f);     // tanh(c)
        float kc = fmaf(ai, ag, (af - 1.0f) * c_ev);         // i*g + f*c - c
        float kh = fmaf(ao, tc, -h_ev);                      // o*tanh(c) - h

        // minimal pre-barrier path: hnx/cnx only (sums deferred except st3)
        float hnx, cnx;
        if (st == 0 || st == 1) {
          hnx = fmaf(hdt, kh, h0v); cnx = fmaf(hdt, kc, c0v);
        } else if (st == 2) {
          hnx = fmaf(dt, kh, h0v); cnx = fmaf(dt, kc, c0v);
        } else {
          float sh = sum_h + kh, sc = sum_c + kc;
          h0v = fmaf(d6, sh, h0v); c0v = fmaf(d6, sc, c0v);
          hnx = h0v; cnx = c0v;
        }

        if (quad == 0) lds_h[(st & 1) ^ 1][n] = (_Float16)hnx;
        if (st == 3 && ode == 3 && t < 32 && s + 1 < S_N) {
          lds_x[2 * t]     = (_Float16)xn0;
          lds_x[2 * t + 1] = (_Float16)xn1;
        }
        __syncthreads();

        // post-barrier bookkeeping (overlaps next stage's LDS latency)
        if (st == 0) {
          sum_h = kh; sum_c = kc;
        } else if (st == 1 || st == 2) {
          sum_h = fmaf(2.f, kh, sum_h); sum_c = fmaf(2.f, kc, sum_c);
        }
        h_ev = hnx; c_ev = cnx;
      }
    }

    if (quad == 0) out[(size_t)(b * S_N + s) * H_N + n] = h0v;
  }
}

extern "C" void kernel_launch(void* const* d_in, const int* in_sizes, int n_in,
                              void* d_out, int out_size, void* d_ws, size_t ws_size,
                              hipStream_t stream) {
  (void)in_sizes; (void)n_in; (void)d_ws; (void)ws_size; (void)out_size;
  clstm_mfma4<<<B_N, 512, 0, stream>>>(
      (const float*)d_in[0],  // x
      (const float*)d_in[1],  // time_diffs
      (const float*)d_in[2], (const float*)d_in[3],   // W_i, b_i
      (const float*)d_in[4], (const float*)d_in[5],   // W_f, b_f
      (const float*)d_in[6], (const float*)d_in[7],   // W_o, b_o
      (const float*)d_in[8], (const float*)d_in[9],   // W_g, b_g
      (float*)d_out);
}